// Round 14
// baseline (345.992 us; speedup 1.0000x reference)
//
#include <hip/hip_runtime.h>

// Qwen3 MoE experts: per-expert SwiGLU MLP.
//   gate = rin @ gate_proj^T ; up = rin @ up_proj^T
//   hidden = silu(gate) * up ; out = hidden @ down_proj^T
// E=32, T=512, H=2048, I=768. f32 inputs; bf16 MFMA, f32 accum.
//
// R14: R13 (3 blocks/CU, the proven streams win) + two fixes:
//  1) bf16-tile swizzle corrected to p = h ^ ((R>>1)&3). Old (R&3) left
//     rows R,R+4,R+8,R+12 in the same banks (64B rows = 16 banks) -> 4-way
//     conflicts, the invariant 1.26e7 counter. Applied to gateup SA/SG/SU
//     reads+staging sources AND moe_down's bf16 A tile.
//  2) depth-2 prefetch for G/U (HBM-missing streams) via parity reg sets;
//     A stays depth-1 (L2-warm). +16 VGPR, still 3 waves/SIMD.
// ws: hidden [E,T,I] bf16 = 24 MB.

#define NE 32
#define NT 512
#define NH 2048
#define NI 768

typedef short        short8  __attribute__((ext_vector_type(8)));
typedef float        floatx4 __attribute__((ext_vector_type(4)));
typedef unsigned int uintx4  __attribute__((ext_vector_type(4)));
typedef __attribute__((address_space(1))) const unsigned int g_u32;
typedef __attribute__((address_space(3))) unsigned int l_u32;

__device__ __forceinline__ void gl_lds16(const void* g, void* l) {
    __builtin_amdgcn_global_load_lds((g_u32*)g, (l_u32*)l, 16, 0, 0);
}

__device__ __forceinline__ unsigned int cvt_pk_bf16(float lo, float hi) {
    unsigned int r;
    asm("v_cvt_pk_bf16_f32 %0, %1, %2" : "=v"(r) : "v"(lo), "v"(hi));
    return r;
}

__device__ __forceinline__ short8 frag8(floatx4 x0, floatx4 x1) {
    union { unsigned int u[4]; short8 s; } t;
    t.u[0] = cvt_pk_bf16(x0[0], x0[1]);
    t.u[1] = cvt_pk_bf16(x0[2], x0[3]);
    t.u[2] = cvt_pk_bf16(x1[0], x1[1]);
    t.u[3] = cvt_pk_bf16(x1[2], x1[3]);
    return t.s;
}

__device__ __forceinline__ uintx4 pack8(floatx4 x0, floatx4 x1) {
    uintx4 u;
    u[0] = cvt_pk_bf16(x0[0], x0[1]);
    u[1] = cvt_pk_bf16(x0[2], x0[3]);
    u[2] = cvt_pk_bf16(x1[0], x1[1]);
    u[3] = cvt_pk_bf16(x1[2], x1[3]);
    return u;
}

__device__ __forceinline__ ushort f2bf(float f) {
    union { float f; unsigned int u; } v; v.f = f;
    unsigned int r = v.u + 0x7fffu + ((v.u >> 16) & 1u);
    return (ushort)(r >> 16);
}

// ---------------------------------------------------------------------------
// Kernel 1: fused gate+up + SwiGLU -> hidden(bf16).
// BM=128(T) x BN=64(I), BK=32 over H. 256 thr = 4 waves (2x2), per GEMM
// 4x2 frags of 16x16 -> acc 64 AGPR. LDS 32 KB -> 3 blocks/CU.
// Swizzle: phys chunk p = logical h ^ ((row>>1)&3)  (2-way max = free).
// Prefetch: A depth-1; G/U depth-2 (parity regs g0/g1).
// ---------------------------------------------------------------------------
__global__ __launch_bounds__(256, 3) void moe_gateup(
    const float* __restrict__ rin, const float* __restrict__ gate,
    const float* __restrict__ up, ushort* __restrict__ hidden)
{
    __shared__ ushort SA[2][128][32];
    __shared__ ushort SG[2][64][32];
    __shared__ ushort SU[2][64][32];

    // XCD-bijective swizzle: 1536 blocks, chunk 192
    const int bid = blockIdx.x;
    const int wg  = (bid & 7) * 192 + (bid >> 3);
    const int e   = wg / 48;
    const int rem = wg % 48;
    const int ti  = rem % 12;   // I tile of 64
    const int tm  = rem / 12;   // T tile of 128

    const int tid  = threadIdx.x;
    const int lane = tid & 63;
    const int wave = tid >> 6;          // 0..3
    const int wr = wave >> 1;           // T band of 64
    const int wc = wave & 1;            // I band of 32

    const float* Ab = rin  + (size_t)e * NT * NH + (size_t)(tm * 128) * NH;
    const float* Gb = gate + (size_t)e * NI * NH + (size_t)(ti * 64) * NH;
    const float* Ub = up   + (size_t)e * NI * NH + (size_t)(ti * 64) * NH;

    // staging geometry: LINEAR phys write, pre-swizzled source
    const int s_row = tid >> 2;                 // 0..63
    const int s_cl  = tid & 3;                  // phys chunk
    const int s_c   = s_cl ^ ((s_row >> 1) & 3);  // logical chunk (source)
    // A slot 1 is row+64: ((row+64)>>1)&3 == (row>>1)&3, same s_c.
    const float* A0src = Ab + (size_t)s_row * NH + s_c * 8;
    const float* A1src = Ab + (size_t)(s_row + 64) * NH + s_c * 8;
    const float* Gsrc  = Gb + (size_t)s_row * NH + s_c * 8;
    const float* Usrc  = Ub + (size_t)s_row * NH + s_c * 8;

    floatx4 accg[4][2], accu[4][2];
    #pragma unroll
    for (int m = 0; m < 4; ++m)
        #pragma unroll
        for (int n = 0; n < 2; ++n) {
            accg[m][n] = (floatx4)0.f;
            accu[m][n] = (floatx4)0.f;
        }

    const int frow = lane & 15;
    const int h    = lane >> 4;                  // logical k-chunk 0..3
    const int pch  = h ^ ((frow >> 1) & 3);      // phys chunk for ALL frags
    const int KT = NH / 32;                      // 64

    floatx4 a[2][2];           // A prefetch [slot][half], depth-1
    floatx4 g0[2][2], g1[2][2]; // G/U prefetch [G,U][half], two parities

#define ISSUE_A(kt) do {                                                     \
        const int k_ = (kt) * 32;                                            \
        a[0][0] = *(const floatx4*)(A0src + k_);                             \
        a[0][1] = *(const floatx4*)(A0src + k_ + 4);                         \
        a[1][0] = *(const floatx4*)(A1src + k_);                             \
        a[1][1] = *(const floatx4*)(A1src + k_ + 4);                         \
    } while (0)

#define ISSUE_G(kt, gp) do {                                                 \
        const int k_ = (kt) * 32;                                            \
        gp[0][0] = *(const floatx4*)(Gsrc + k_);                             \
        gp[0][1] = *(const floatx4*)(Gsrc + k_ + 4);                         \
        gp[1][0] = *(const floatx4*)(Usrc + k_);                             \
        gp[1][1] = *(const floatx4*)(Usrc + k_ + 4);                         \
    } while (0)

#define WRITE(b, gp) do {                                                    \
        *(uintx4*)&SA[b][s_row][s_cl * 8]      = pack8(a[0][0], a[0][1]);    \
        *(uintx4*)&SA[b][s_row + 64][s_cl * 8] = pack8(a[1][0], a[1][1]);    \
        *(uintx4*)&SG[b][s_row][s_cl * 8]      = pack8(gp[0][0], gp[0][1]);  \
        *(uintx4*)&SU[b][s_row][s_cl * 8]      = pack8(gp[1][0], gp[1][1]);  \
    } while (0)

#define COMPUTE(b) do {                                                      \
        short8 af[4], gf[2], uf[2];                                          \
        _Pragma("unroll")                                                    \
        for (int m = 0; m < 4; ++m)                                          \
            af[m] = *(const short8*)&SA[b][wr * 64 + m * 16 + frow][pch * 8];\
        _Pragma("unroll")                                                    \
        for (int n = 0; n < 2; ++n) {                                        \
            gf[n] = *(const short8*)&SG[b][wc * 32 + n * 16 + frow][pch * 8];\
            uf[n] = *(const short8*)&SU[b][wc * 32 + n * 16 + frow][pch * 8];\
        }                                                                    \
        _Pragma("unroll")                                                    \
        for (int m = 0; m < 4; ++m)                                          \
            _Pragma("unroll")                                                \
            for (int n = 0; n < 2; ++n) {                                    \
                accg[m][n] = __builtin_amdgcn_mfma_f32_16x16x32_bf16(        \
                    af[m], gf[n], accg[m][n], 0, 0, 0);                      \
                accu[m][n] = __builtin_amdgcn_mfma_f32_16x16x32_bf16(        \
                    af[m], uf[n], accu[m][n], 0, 0, 0);                      \
            }                                                                \
    } while (0)

#define ENDBAR() do {                                                        \
        asm volatile("s_waitcnt lgkmcnt(0)" ::: "memory");                   \
        __builtin_amdgcn_sched_barrier(0);                                   \
        __builtin_amdgcn_s_barrier();                                        \
    } while (0)

    // prologue: tile0 -> buf0 (via a,g0); a<-1, g0<-2 in flight; g1<-1.
    ISSUE_A(0);
    ISSUE_G(0, g0);
    ISSUE_G(1, g1);
    WRITE(0, g0);
    ISSUE_A(1);
    ISSUE_G(2, g0);
    ENDBAR();

    for (int kt = 0; kt < KT; kt += 2) {
        // buf0 = tile kt. a=kt+1, g1=kt+1 (landed); g0=kt+2 (in flight).
        COMPUTE(0);
        if (kt + 1 < KT) {
            WRITE(1, g1);
            if (kt + 2 < KT) ISSUE_A(kt + 2);
            if (kt + 3 < KT) ISSUE_G(kt + 3, g1);
        }
        ENDBAR();
        // buf1 = tile kt+1. a=kt+2, g0=kt+2; g1=kt+3 (in flight).
        COMPUTE(1);
        if (kt + 2 < KT) {
            WRITE(0, g0);
            if (kt + 3 < KT) ISSUE_A(kt + 3);
            if (kt + 4 < KT) ISSUE_G(kt + 4, g0);
        }
        ENDBAR();
    }
#undef ISSUE_A
#undef ISSUE_G
#undef WRITE
#undef COMPUTE
#undef ENDBAR

    // Epilogue: silu(g)*u -> bf16. C/D: col=lane&15, row=(lane>>4)*4+reg.
    const int ccol  = lane & 15;
    const int crow0 = (lane >> 4) * 4;
    const size_t hbase = ((size_t)e * NT + (size_t)tm * 128) * NI + ti * 64;
    #pragma unroll
    for (int m = 0; m < 4; ++m)
        #pragma unroll
        for (int n = 0; n < 2; ++n)
            #pragma unroll
            for (int j = 0; j < 4; ++j) {
                const float g = accg[m][n][j];
                const float u = accu[m][n][j];
                const float hh = (g / (1.f + __expf(-g))) * u;
                const int row = wr * 64 + m * 16 + crow0 + j;
                const int col = wc * 32 + n * 16 + ccol;
                hidden[hbase + (size_t)row * NI + col] = f2bf(hh);
            }
}

// ---------------------------------------------------------------------------
// Kernel 2: down projection. Same as R13 except the bf16 A-tile swizzle is
// corrected to the ((row>>1)&3) form (source AND read side).
// ---------------------------------------------------------------------------
__global__ __launch_bounds__(256, 2) void moe_down(
    const ushort* __restrict__ hidden, const float* __restrict__ down,
    float* __restrict__ out)
{
    __shared__ ushort As[2][128][32];
    __shared__ float  Bs[2][128][32];

    const int bid = blockIdx.x;
    const int wg  = (bid & 7) * (2048 / 8) + (bid >> 3);
    const int e   = wg >> 6;
    const int rem = wg & 63;
    const int tn  = rem & 15;
    const int tm  = rem >> 4;

    const int tid  = threadIdx.x;
    const int lane = tid & 63;
    const int wave = tid >> 6;
    const int wr = wave >> 1, wc = wave & 1;

    const ushort* Ab = hidden + ((size_t)e * NT + (size_t)tm * 128) * NI;
    const float*  Bb = down + (size_t)e * NH * NI + (size_t)(tn * 128) * NI;

    floatx4 acc[4][4];
    #pragma unroll
    for (int m = 0; m < 4; ++m)
        #pragma unroll
        for (int n = 0; n < 4; ++n) acc[m][n] = (floatx4)0.f;

    const int frow = lane & 15;
    const int h    = lane >> 4;
    const int ca   = h ^ ((frow >> 1) & 3);   // fixed swizzle (2-way max)
    const int rb   = frow & 7;
    const int c0   = (2 * h) ^ rb;
    const int c1   = (2 * h + 1) ^ rb;
    const int KT = NI / 32;

#define STAGE_DN(kt, b) do {                                                 \
        const int k0_ = (kt) * 32;                                           \
        _Pragma("unroll")                                                    \
        for (int i = 0; i < 2; ++i) {                                        \
            const int g_ = wave * 2 + i;                                     \
            const int r_ = g_ * 16 + (lane >> 2);                            \
            const int cs_ = (lane & 3) ^ ((r_ >> 1) & 3);                    \
            gl_lds16(Ab + (size_t)r_ * NI + k0_ + cs_ * 8, &As[b][g_ * 16][0]); \
        }                                                                    \
        _Pragma("unroll")                                                    \
        for (int i = 0; i < 4; ++i) {                                        \
            const int g_ = wave * 4 + i;                                     \
            const int r_ = g_ * 8 + (lane >> 3);                             \
            const int cs_ = (lane & 7) ^ (r_ & 7);                           \
            gl_lds16(Bb + (size_t)r_ * NI + k0_ + cs_ * 4, &Bs[b][g_ * 8][0]); \
        }                                                                    \
    } while (0)

    STAGE_DN(0, 0);

    for (int kt = 0; kt < KT; ++kt) {
        const int cur = kt & 1;
        if (kt + 1 < KT) {
            STAGE_DN(kt + 1, cur ^ 1);
            asm volatile("s_waitcnt vmcnt(6)" ::: "memory");
        } else {
            asm volatile("s_waitcnt vmcnt(0)" ::: "memory");
        }
        __builtin_amdgcn_s_barrier();

        short8 af[4], bf[4];
        #pragma unroll
        for (int m = 0; m < 4; ++m) {
            const int R = wr * 64 + m * 16 + frow;
            af[m] = *(const short8*)&As[cur][R][ca * 8];
        }
        #pragma unroll
        for (int n = 0; n < 4; ++n) {
            const int R = wc * 64 + n * 16 + frow;
            bf[n] = frag8(*(const floatx4*)&Bs[cur][R][c0 * 4],
                          *(const floatx4*)&Bs[cur][R][c1 * 4]);
        }
        #pragma unroll
        for (int m = 0; m < 4; ++m)
            #pragma unroll
            for (int n = 0; n < 4; ++n)
                acc[m][n] = __builtin_amdgcn_mfma_f32_16x16x32_bf16(
                    af[m], bf[n], acc[m][n], 0, 0, 0);

        asm volatile("s_waitcnt lgkmcnt(0)" ::: "memory");
        __builtin_amdgcn_sched_barrier(0);
        __builtin_amdgcn_s_barrier();
    }
#undef STAGE_DN

    const int ccol  = lane & 15;
    const int crow0 = (lane >> 4) * 4;
    float* Ob = out + ((size_t)e * NT + (size_t)tm * 128) * NH + tn * 128;
    #pragma unroll
    for (int m = 0; m < 4; ++m)
        #pragma unroll
        for (int n = 0; n < 4; ++n)
            #pragma unroll
            for (int j = 0; j < 4; ++j) {
                const int row = wr * 64 + m * 16 + crow0 + j;
                const int col = wc * 64 + n * 16 + ccol;
                Ob[(size_t)row * NH + col] = acc[m][n][j];
            }
}

extern "C" void kernel_launch(void* const* d_in, const int* in_sizes, int n_in,
                              void* d_out, int out_size, void* d_ws, size_t ws_size,
                              hipStream_t stream) {
    const float* rin  = (const float*)d_in[0];
    const float* gate = (const float*)d_in[1];
    const float* up   = (const float*)d_in[2];
    const float* down = (const float*)d_in[3];
    float* out = (float*)d_out;
    ushort* hidden = (ushort*)d_ws;   // [E,T,I] bf16, 24 MB

    moe_gateup<<<dim3(1536), dim3(256), 0, stream>>>(rin, gate, up, hidden);
    moe_down<<<dim3(2048), dim3(256), 0, stream>>>(hidden, down, out);
}

// Round 15
// 340.132 us; speedup vs baseline: 1.0172x; 1.0172x over previous
//
#include <hip/hip_runtime.h>

// Qwen3 MoE experts: per-expert SwiGLU MLP.
//   gate = rin @ gate_proj^T ; up = rin @ up_proj^T
//   hidden = silu(gate) * up ; out = hidden @ down_proj^T
// E=32, T=512, H=2048, I=768. f32 inputs; bf16 MFMA, f32 accum.
//
// R15: merge of measured-best components (no new structure):
//  - gateup: R13's exact schedule (3 blocks/CU, depth-1 reg prefetch,
//    COMPUTE->WRITE->ISSUE, 245us measured) with R14's verified
//    conflict-free swizzle p = h ^ ((row>>1)&3) (R14: counter -> 0).
//    R14's depth-2 G/U parity prefetch REVERTED (cost ~20us, no benefit).
//  - down: R14's (A-tile swizzle fixed, ~70-80us).
// ws: hidden [E,T,I] bf16 = 24 MB.

#define NE 32
#define NT 512
#define NH 2048
#define NI 768

typedef short        short8  __attribute__((ext_vector_type(8)));
typedef float        floatx4 __attribute__((ext_vector_type(4)));
typedef unsigned int uintx4  __attribute__((ext_vector_type(4)));
typedef __attribute__((address_space(1))) const unsigned int g_u32;
typedef __attribute__((address_space(3))) unsigned int l_u32;

__device__ __forceinline__ void gl_lds16(const void* g, void* l) {
    __builtin_amdgcn_global_load_lds((g_u32*)g, (l_u32*)l, 16, 0, 0);
}

__device__ __forceinline__ unsigned int cvt_pk_bf16(float lo, float hi) {
    unsigned int r;
    asm("v_cvt_pk_bf16_f32 %0, %1, %2" : "=v"(r) : "v"(lo), "v"(hi));
    return r;
}

__device__ __forceinline__ short8 frag8(floatx4 x0, floatx4 x1) {
    union { unsigned int u[4]; short8 s; } t;
    t.u[0] = cvt_pk_bf16(x0[0], x0[1]);
    t.u[1] = cvt_pk_bf16(x0[2], x0[3]);
    t.u[2] = cvt_pk_bf16(x1[0], x1[1]);
    t.u[3] = cvt_pk_bf16(x1[2], x1[3]);
    return t.s;
}

__device__ __forceinline__ uintx4 pack8(floatx4 x0, floatx4 x1) {
    uintx4 u;
    u[0] = cvt_pk_bf16(x0[0], x0[1]);
    u[1] = cvt_pk_bf16(x0[2], x0[3]);
    u[2] = cvt_pk_bf16(x1[0], x1[1]);
    u[3] = cvt_pk_bf16(x1[2], x1[3]);
    return u;
}

__device__ __forceinline__ ushort f2bf(float f) {
    union { float f; unsigned int u; } v; v.f = f;
    unsigned int r = v.u + 0x7fffu + ((v.u >> 16) & 1u);
    return (ushort)(r >> 16);
}

// ---------------------------------------------------------------------------
// Kernel 1: fused gate+up + SwiGLU -> hidden(bf16).
// BM=128(T) x BN=64(I), BK=32 over H. 256 thr = 4 waves (2x2), per GEMM
// 4x2 frags of 16x16 -> acc 64 AGPR. LDS 32 KB -> 3 blocks/CU.
// Swizzle: phys chunk p = h ^ ((row>>1)&3) — verified conflict-free (R14).
// Prefetch: depth-1 reg staging, COMPUTE->WRITE->ISSUE order (R13).
// ---------------------------------------------------------------------------
__global__ __launch_bounds__(256, 3) void moe_gateup(
    const float* __restrict__ rin, const float* __restrict__ gate,
    const float* __restrict__ up, ushort* __restrict__ hidden)
{
    __shared__ ushort SA[2][128][32];
    __shared__ ushort SG[2][64][32];
    __shared__ ushort SU[2][64][32];

    // XCD-bijective swizzle: 1536 blocks, chunk 192
    const int bid = blockIdx.x;
    const int wg  = (bid & 7) * 192 + (bid >> 3);
    const int e   = wg / 48;
    const int rem = wg % 48;
    const int ti  = rem % 12;   // I tile of 64
    const int tm  = rem / 12;   // T tile of 128

    const int tid  = threadIdx.x;
    const int lane = tid & 63;
    const int wave = tid >> 6;          // 0..3
    const int wr = wave >> 1;           // T band of 64
    const int wc = wave & 1;            // I band of 32

    const float* Ab = rin  + (size_t)e * NT * NH + (size_t)(tm * 128) * NH;
    const float* Gb = gate + (size_t)e * NI * NH + (size_t)(ti * 64) * NH;
    const float* Ub = up   + (size_t)e * NI * NH + (size_t)(ti * 64) * NH;

    // staging geometry: LINEAR phys write, pre-swizzled source
    const int s_row = tid >> 2;                    // 0..63
    const int s_cl  = tid & 3;                     // phys chunk
    const int s_c   = s_cl ^ ((s_row >> 1) & 3);   // logical chunk (source)
    // A slot 1 row+64: ((row+64)>>1)&3 == (row>>1)&3 -> same s_c.
    const float* A0src = Ab + (size_t)s_row * NH + s_c * 8;
    const float* A1src = Ab + (size_t)(s_row + 64) * NH + s_c * 8;
    const float* Gsrc  = Gb + (size_t)s_row * NH + s_c * 8;
    const float* Usrc  = Ub + (size_t)s_row * NH + s_c * 8;

    floatx4 accg[4][2], accu[4][2];
    #pragma unroll
    for (int m = 0; m < 4; ++m)
        #pragma unroll
        for (int n = 0; n < 2; ++n) {
            accg[m][n] = (floatx4)0.f;
            accu[m][n] = (floatx4)0.f;
        }

    const int frow = lane & 15;
    const int h    = lane >> 4;                    // logical k-chunk 0..3
    const int pch  = h ^ ((frow >> 1) & 3);        // phys chunk for frags
    const int KT = NH / 32;                        // 64

    floatx4 P[4][2];   // [A0,A1,G,U][half] prefetch regs (32 VGPR)

#define ISSUE(kt) do {                                                       \
        const int k_ = (kt) * 32;                                            \
        P[0][0] = *(const floatx4*)(A0src + k_);                             \
        P[0][1] = *(const floatx4*)(A0src + k_ + 4);                         \
        P[1][0] = *(const floatx4*)(A1src + k_);                             \
        P[1][1] = *(const floatx4*)(A1src + k_ + 4);                         \
        P[2][0] = *(const floatx4*)(Gsrc + k_);                              \
        P[2][1] = *(const floatx4*)(Gsrc + k_ + 4);                          \
        P[3][0] = *(const floatx4*)(Usrc + k_);                              \
        P[3][1] = *(const floatx4*)(Usrc + k_ + 4);                          \
    } while (0)

#define WRITE(b) do {                                                        \
        *(uintx4*)&SA[b][s_row][s_cl * 8]      = pack8(P[0][0], P[0][1]);    \
        *(uintx4*)&SA[b][s_row + 64][s_cl * 8] = pack8(P[1][0], P[1][1]);    \
        *(uintx4*)&SG[b][s_row][s_cl * 8]      = pack8(P[2][0], P[2][1]);    \
        *(uintx4*)&SU[b][s_row][s_cl * 8]      = pack8(P[3][0], P[3][1]);    \
    } while (0)

#define COMPUTE(b) do {                                                      \
        short8 af[4], gf[2], uf[2];                                          \
        _Pragma("unroll")                                                    \
        for (int m = 0; m < 4; ++m)                                          \
            af[m] = *(const short8*)&SA[b][wr * 64 + m * 16 + frow][pch * 8];\
        _Pragma("unroll")                                                    \
        for (int n = 0; n < 2; ++n) {                                        \
            gf[n] = *(const short8*)&SG[b][wc * 32 + n * 16 + frow][pch * 8];\
            uf[n] = *(const short8*)&SU[b][wc * 32 + n * 16 + frow][pch * 8];\
        }                                                                    \
        _Pragma("unroll")                                                    \
        for (int m = 0; m < 4; ++m)                                          \
            _Pragma("unroll")                                                \
            for (int n = 0; n < 2; ++n) {                                    \
                accg[m][n] = __builtin_amdgcn_mfma_f32_16x16x32_bf16(        \
                    af[m], gf[n], accg[m][n], 0, 0, 0);                      \
                accu[m][n] = __builtin_amdgcn_mfma_f32_16x16x32_bf16(        \
                    af[m], uf[n], accu[m][n], 0, 0, 0);                      \
            }                                                                \
    } while (0)

#define ENDBAR() do {                                                        \
        asm volatile("s_waitcnt lgkmcnt(0)" ::: "memory");                   \
        __builtin_amdgcn_sched_barrier(0);                                   \
        __builtin_amdgcn_s_barrier();                                        \
    } while (0)

    // prologue: tile 0 -> buf0; tile 1 loads in flight
    ISSUE(0);
    WRITE(0);
    ISSUE(1);
    ENDBAR();

    for (int kt = 0; kt < KT; kt += 2) {
        // iter kt: compute buf0(tile kt); write tile kt+1 -> buf1 (its loads
        // issued one compute-phase ago); issue tile kt+2.
        COMPUTE(0);
        WRITE(1);
        if (kt + 2 < KT) ISSUE(kt + 2);
        ENDBAR();
        // iter kt+1
        COMPUTE(1);
        if (kt + 2 < KT) WRITE(0);
        if (kt + 3 < KT) ISSUE(kt + 3);
        ENDBAR();
    }
#undef ISSUE
#undef WRITE
#undef COMPUTE
#undef ENDBAR

    // Epilogue: silu(g)*u -> bf16. C/D: col=lane&15, row=(lane>>4)*4+reg.
    const int ccol  = lane & 15;
    const int crow0 = (lane >> 4) * 4;
    const size_t hbase = ((size_t)e * NT + (size_t)tm * 128) * NI + ti * 64;
    #pragma unroll
    for (int m = 0; m < 4; ++m)
        #pragma unroll
        for (int n = 0; n < 2; ++n)
            #pragma unroll
            for (int j = 0; j < 4; ++j) {
                const float g = accg[m][n][j];
                const float u = accu[m][n][j];
                const float hh = (g / (1.f + __expf(-g))) * u;
                const int row = wr * 64 + m * 16 + crow0 + j;
                const int col = wc * 32 + n * 16 + ccol;
                hidden[hbase + (size_t)row * NI + col] = f2bf(hh);
            }
}

// ---------------------------------------------------------------------------
// Kernel 2: down projection (R14's: A-tile swizzle in ((row>>1)&3) form).
// ---------------------------------------------------------------------------
__global__ __launch_bounds__(256, 2) void moe_down(
    const ushort* __restrict__ hidden, const float* __restrict__ down,
    float* __restrict__ out)
{
    __shared__ ushort As[2][128][32];
    __shared__ float  Bs[2][128][32];

    const int bid = blockIdx.x;
    const int wg  = (bid & 7) * (2048 / 8) + (bid >> 3);
    const int e   = wg >> 6;
    const int rem = wg & 63;
    const int tn  = rem & 15;
    const int tm  = rem >> 4;

    const int tid  = threadIdx.x;
    const int lane = tid & 63;
    const int wave = tid >> 6;
    const int wr = wave >> 1, wc = wave & 1;

    const ushort* Ab = hidden + ((size_t)e * NT + (size_t)tm * 128) * NI;
    const float*  Bb = down + (size_t)e * NH * NI + (size_t)(tn * 128) * NI;

    floatx4 acc[4][4];
    #pragma unroll
    for (int m = 0; m < 4; ++m)
        #pragma unroll
        for (int n = 0; n < 4; ++n) acc[m][n] = (floatx4)0.f;

    const int frow = lane & 15;
    const int h    = lane >> 4;
    const int ca   = h ^ ((frow >> 1) & 3);   // conflict-free form
    const int rb   = frow & 7;
    const int c0   = (2 * h) ^ rb;
    const int c1   = (2 * h + 1) ^ rb;
    const int KT = NI / 32;

#define STAGE_DN(kt, b) do {                                                 \
        const int k0_ = (kt) * 32;                                           \
        _Pragma("unroll")                                                    \
        for (int i = 0; i < 2; ++i) {                                        \
            const int g_ = wave * 2 + i;                                     \
            const int r_ = g_ * 16 + (lane >> 2);                            \
            const int cs_ = (lane & 3) ^ ((r_ >> 1) & 3);                    \
            gl_lds16(Ab + (size_t)r_ * NI + k0_ + cs_ * 8, &As[b][g_ * 16][0]); \
        }                                                                    \
        _Pragma("unroll")                                                    \
        for (int i = 0; i < 4; ++i) {                                        \
            const int g_ = wave * 4 + i;                                     \
            const int r_ = g_ * 8 + (lane >> 3);                             \
            const int cs_ = (lane & 7) ^ (r_ & 7);                           \
            gl_lds16(Bb + (size_t)r_ * NI + k0_ + cs_ * 4, &Bs[b][g_ * 8][0]); \
        }                                                                    \
    } while (0)

    STAGE_DN(0, 0);

    for (int kt = 0; kt < KT; ++kt) {
        const int cur = kt & 1;
        if (kt + 1 < KT) {
            STAGE_DN(kt + 1, cur ^ 1);
            asm volatile("s_waitcnt vmcnt(6)" ::: "memory");
        } else {
            asm volatile("s_waitcnt vmcnt(0)" ::: "memory");
        }
        __builtin_amdgcn_s_barrier();

        short8 af[4], bf[4];
        #pragma unroll
        for (int m = 0; m < 4; ++m) {
            const int R = wr * 64 + m * 16 + frow;
            af[m] = *(const short8*)&As[cur][R][ca * 8];
        }
        #pragma unroll
        for (int n = 0; n < 4; ++n) {
            const int R = wc * 64 + n * 16 + frow;
            bf[n] = frag8(*(const floatx4*)&Bs[cur][R][c0 * 4],
                          *(const floatx4*)&Bs[cur][R][c1 * 4]);
        }
        #pragma unroll
        for (int m = 0; m < 4; ++m)
            #pragma unroll
            for (int n = 0; n < 4; ++n)
                acc[m][n] = __builtin_amdgcn_mfma_f32_16x16x32_bf16(
                    af[m], bf[n], acc[m][n], 0, 0, 0);

        asm volatile("s_waitcnt lgkmcnt(0)" ::: "memory");
        __builtin_amdgcn_sched_barrier(0);
        __builtin_amdgcn_s_barrier();
    }
#undef STAGE_DN

    const int ccol  = lane & 15;
    const int crow0 = (lane >> 4) * 4;
    float* Ob = out + ((size_t)e * NT + (size_t)tm * 128) * NH + tn * 128;
    #pragma unroll
    for (int m = 0; m < 4; ++m)
        #pragma unroll
        for (int n = 0; n < 4; ++n)
            #pragma unroll
            for (int j = 0; j < 4; ++j) {
                const int row = wr * 64 + m * 16 + crow0 + j;
                const int col = wc * 64 + n * 16 + ccol;
                Ob[(size_t)row * NH + col] = acc[m][n][j];
            }
}

extern "C" void kernel_launch(void* const* d_in, const int* in_sizes, int n_in,
                              void* d_out, int out_size, void* d_ws, size_t ws_size,
                              hipStream_t stream) {
    const float* rin  = (const float*)d_in[0];
    const float* gate = (const float*)d_in[1];
    const float* up   = (const float*)d_in[2];
    const float* down = (const float*)d_in[3];
    float* out = (float*)d_out;
    ushort* hidden = (ushort*)d_ws;   // [E,T,I] bf16, 24 MB

    moe_gateup<<<dim3(1536), dim3(256), 0, stream>>>(rin, gate, up, hidden);
    moe_down<<<dim3(2048), dim3(256), 0, stream>>>(hidden, down, out);
}

// Round 16
// 335.005 us; speedup vs baseline: 1.0328x; 1.0153x over previous
//
#include <hip/hip_runtime.h>

// Qwen3 MoE experts: per-expert SwiGLU MLP.
//   gate = rin @ gate_proj^T ; up = rin @ up_proj^T
//   hidden = silu(gate) * up ; out = hidden @ down_proj^T
// E=32, T=512, H=2048, I=768. f32 inputs; bf16 MFMA, f32 accum.
//
// R16 = R13 verbatim (session-best 336.5us), terminal confirm round.
// 15-round ablation summary:
//  - streams/CU was the only monotone lever: {1,2,3} blocks -> gateup
//    {~290, ~270, 245}us. 4 blocks needs <=128 regs/thread: impossible
//    with 64-AGPR acc + staging regs.
//  - bank conflicts (1.26e7) are fully latency-hidden: fixing them (R14/R15,
//    counter -> 0) made gateup SLOWER (~15us) via worse L2 access order.
//  - prefetch depth >1 regressed in all 5 attempts (R3/R7/R8/R10/R14).
//  - down is at the ds_read_b128 throughput ceiling (~736 TF effective).
// ws: hidden [E,T,I] bf16 = 24 MB.

#define NE 32
#define NT 512
#define NH 2048
#define NI 768

typedef short        short8  __attribute__((ext_vector_type(8)));
typedef float        floatx4 __attribute__((ext_vector_type(4)));
typedef unsigned int uintx4  __attribute__((ext_vector_type(4)));
typedef __attribute__((address_space(1))) const unsigned int g_u32;
typedef __attribute__((address_space(3))) unsigned int l_u32;

__device__ __forceinline__ void gl_lds16(const void* g, void* l) {
    __builtin_amdgcn_global_load_lds((g_u32*)g, (l_u32*)l, 16, 0, 0);
}

__device__ __forceinline__ unsigned int cvt_pk_bf16(float lo, float hi) {
    unsigned int r;
    asm("v_cvt_pk_bf16_f32 %0, %1, %2" : "=v"(r) : "v"(lo), "v"(hi));
    return r;
}

__device__ __forceinline__ short8 frag8(floatx4 x0, floatx4 x1) {
    union { unsigned int u[4]; short8 s; } t;
    t.u[0] = cvt_pk_bf16(x0[0], x0[1]);
    t.u[1] = cvt_pk_bf16(x0[2], x0[3]);
    t.u[2] = cvt_pk_bf16(x1[0], x1[1]);
    t.u[3] = cvt_pk_bf16(x1[2], x1[3]);
    return t.s;
}

__device__ __forceinline__ uintx4 pack8(floatx4 x0, floatx4 x1) {
    uintx4 u;
    u[0] = cvt_pk_bf16(x0[0], x0[1]);
    u[1] = cvt_pk_bf16(x0[2], x0[3]);
    u[2] = cvt_pk_bf16(x1[0], x1[1]);
    u[3] = cvt_pk_bf16(x1[2], x1[3]);
    return u;
}

__device__ __forceinline__ ushort f2bf(float f) {
    union { float f; unsigned int u; } v; v.f = f;
    unsigned int r = v.u + 0x7fffu + ((v.u >> 16) & 1u);
    return (ushort)(r >> 16);
}

// ---------------------------------------------------------------------------
// Kernel 1: fused gate+up + SwiGLU -> hidden(bf16).
// BM=128(T) x BN=64(I), BK=32 over H. 256 thr = 4 waves (2x2), per GEMM
// 4x2 frags of 16x16 -> acc 64 AGPR. LDS 32 KB -> 3 blocks/CU (the lever).
// Reg-staged bf16 dbuf, COMPUTE->WRITE->ISSUE order, compiler-tracked
// load waits, raw s_barrier + lgkmcnt(0) only.
// ---------------------------------------------------------------------------
__global__ __launch_bounds__(256, 3) void moe_gateup(
    const float* __restrict__ rin, const float* __restrict__ gate,
    const float* __restrict__ up, ushort* __restrict__ hidden)
{
    __shared__ ushort SA[2][128][32];
    __shared__ ushort SG[2][64][32];
    __shared__ ushort SU[2][64][32];

    // XCD-bijective swizzle: 1536 blocks, chunk 192
    const int bid = blockIdx.x;
    const int wg  = (bid & 7) * 192 + (bid >> 3);
    const int e   = wg / 48;
    const int rem = wg % 48;
    const int ti  = rem % 12;   // I tile of 64
    const int tm  = rem / 12;   // T tile of 128

    const int tid  = threadIdx.x;
    const int lane = tid & 63;
    const int wave = tid >> 6;          // 0..3
    const int wr = wave >> 1;           // 0..1: T band of 64
    const int wc = wave & 1;            // 0..1: I band of 32

    const float* Ab = rin  + (size_t)e * NT * NH + (size_t)(tm * 128) * NH;
    const float* Gb = gate + (size_t)e * NI * NH + (size_t)(ti * 64) * NH;
    const float* Ub = up   + (size_t)e * NI * NH + (size_t)(ti * 64) * NH;

    // staging geometry (phys chunk LINEAR, source pre-swizzled)
    const int a0_row = tid >> 2,            a0_cl = tid & 3;
    const int a1_row = (tid + 256) >> 2,    a1_cl = tid & 3;
    const int a0_c = a0_cl ^ (a0_row & 3);
    const int a1_c = a1_cl ^ (a1_row & 3);
    const int w_row = tid >> 2,             w_cl = tid & 3;
    const int w_c = w_cl ^ (w_row & 3);

    const float* A0src = Ab + (size_t)a0_row * NH + a0_c * 8;
    const float* A1src = Ab + (size_t)a1_row * NH + a1_c * 8;
    const float* Gsrc  = Gb + (size_t)w_row * NH + w_c * 8;
    const float* Usrc  = Ub + (size_t)w_row * NH + w_c * 8;

    floatx4 accg[4][2], accu[4][2];
    #pragma unroll
    for (int m = 0; m < 4; ++m)
        #pragma unroll
        for (int n = 0; n < 2; ++n) {
            accg[m][n] = (floatx4)0.f;
            accu[m][n] = (floatx4)0.f;
        }

    const int frow = lane & 15;
    const int h    = lane >> 4;          // logical k-chunk 0..3
    const int KT = NH / 32;              // 64

    floatx4 P[4][2];   // [A0,A1,G,U][half] prefetch regs (32 VGPR)

#define ISSUE(kt) do {                                                       \
        const int k_ = (kt) * 32;                                            \
        P[0][0] = *(const floatx4*)(A0src + k_);                             \
        P[0][1] = *(const floatx4*)(A0src + k_ + 4);                         \
        P[1][0] = *(const floatx4*)(A1src + k_);                             \
        P[1][1] = *(const floatx4*)(A1src + k_ + 4);                         \
        P[2][0] = *(const floatx4*)(Gsrc + k_);                              \
        P[2][1] = *(const floatx4*)(Gsrc + k_ + 4);                          \
        P[3][0] = *(const floatx4*)(Usrc + k_);                              \
        P[3][1] = *(const floatx4*)(Usrc + k_ + 4);                          \
    } while (0)

#define WRITE(b) do {                                                       \
        *(uintx4*)&SA[b][a0_row][a0_cl * 8] = pack8(P[0][0], P[0][1]);       \
        *(uintx4*)&SA[b][a1_row][a1_cl * 8] = pack8(P[1][0], P[1][1]);       \
        *(uintx4*)&SG[b][w_row][w_cl * 8]   = pack8(P[2][0], P[2][1]);       \
        *(uintx4*)&SU[b][w_row][w_cl * 8]   = pack8(P[3][0], P[3][1]);       \
    } while (0)

#define COMPUTE(b) do {                                                      \
        short8 af[4], gf[2], uf[2];                                          \
        _Pragma("unroll")                                                    \
        for (int m = 0; m < 4; ++m) {                                        \
            const int R = wr * 64 + m * 16 + frow;                           \
            const int p = h ^ (R & 3);                                       \
            af[m] = *(const short8*)&SA[b][R][p * 8];                        \
        }                                                                    \
        _Pragma("unroll")                                                    \
        for (int n = 0; n < 2; ++n) {                                        \
            const int R = wc * 32 + n * 16 + frow;                           \
            const int p = h ^ (R & 3);                                       \
            gf[n] = *(const short8*)&SG[b][R][p * 8];                        \
            uf[n] = *(const short8*)&SU[b][R][p * 8];                        \
        }                                                                    \
        _Pragma("unroll")                                                    \
        for (int m = 0; m < 4; ++m)                                          \
            _Pragma("unroll")                                                \
            for (int n = 0; n < 2; ++n) {                                    \
                accg[m][n] = __builtin_amdgcn_mfma_f32_16x16x32_bf16(        \
                    af[m], gf[n], accg[m][n], 0, 0, 0);                      \
                accu[m][n] = __builtin_amdgcn_mfma_f32_16x16x32_bf16(        \
                    af[m], uf[n], accu[m][n], 0, 0, 0);                      \
            }                                                                \
    } while (0)

#define ENDBAR() do {                                                        \
        asm volatile("s_waitcnt lgkmcnt(0)" ::: "memory");                   \
        __builtin_amdgcn_sched_barrier(0);                                   \
        __builtin_amdgcn_s_barrier();                                        \
    } while (0)

    // prologue: tile 0 -> buf0; tile 1 loads in flight
    ISSUE(0);
    WRITE(0);
    ISSUE(1);
    ENDBAR();

    for (int kt = 0; kt < KT; kt += 2) {
        COMPUTE(0);
        WRITE(1);
        if (kt + 2 < KT) ISSUE(kt + 2);
        ENDBAR();
        COMPUTE(1);
        if (kt + 2 < KT) WRITE(0);
        if (kt + 3 < KT) ISSUE(kt + 3);
        ENDBAR();
    }
#undef ISSUE
#undef WRITE
#undef COMPUTE
#undef ENDBAR

    // Epilogue: silu(g)*u -> bf16. C/D: col=lane&15, row=(lane>>4)*4+reg.
    const int ccol  = lane & 15;
    const int crow0 = (lane >> 4) * 4;
    const size_t hbase = ((size_t)e * NT + (size_t)tm * 128) * NI + ti * 64;
    #pragma unroll
    for (int m = 0; m < 4; ++m)
        #pragma unroll
        for (int n = 0; n < 2; ++n)
            #pragma unroll
            for (int j = 0; j < 4; ++j) {
                const float g = accg[m][n][j];
                const float u = accu[m][n][j];
                const float hh = (g / (1.f + __expf(-g))) * u;
                const int row = wr * 64 + m * 16 + crow0 + j;
                const int col = wc * 32 + n * 16 + ccol;
                hidden[hbase + (size_t)row * NI + col] = f2bf(hh);
            }
}

// ---------------------------------------------------------------------------
// Kernel 2: down projection (gl_lds dbuf, counted vmcnt, 2 blocks/CU —
// at the ds_read_b128 throughput ceiling, ~736 TF effective).
// ---------------------------------------------------------------------------
__global__ __launch_bounds__(256, 2) void moe_down(
    const ushort* __restrict__ hidden, const float* __restrict__ down,
    float* __restrict__ out)
{
    __shared__ ushort As[2][128][32];
    __shared__ float  Bs[2][128][32];

    const int bid = blockIdx.x;
    const int wg  = (bid & 7) * (2048 / 8) + (bid >> 3);
    const int e   = wg >> 6;
    const int rem = wg & 63;
    const int tn  = rem & 15;
    const int tm  = rem >> 4;

    const int tid  = threadIdx.x;
    const int lane = tid & 63;
    const int wave = tid >> 6;
    const int wr = wave >> 1, wc = wave & 1;

    const ushort* Ab = hidden + ((size_t)e * NT + (size_t)tm * 128) * NI;
    const float*  Bb = down + (size_t)e * NH * NI + (size_t)(tn * 128) * NI;

    floatx4 acc[4][4];
    #pragma unroll
    for (int m = 0; m < 4; ++m)
        #pragma unroll
        for (int n = 0; n < 4; ++n) acc[m][n] = (floatx4)0.f;

    const int frow = lane & 15;
    const int h    = lane >> 4;
    const int ca   = h ^ (frow & 3);
    const int rb   = frow & 7;
    const int c0   = (2 * h) ^ rb;
    const int c1   = (2 * h + 1) ^ rb;
    const int KT = NI / 32;

#define STAGE_DN(kt, b) do {                                                 \
        const int k0_ = (kt) * 32;                                           \
        _Pragma("unroll")                                                    \
        for (int i = 0; i < 2; ++i) {                                        \
            const int g_ = wave * 2 + i;                                     \
            const int r_ = g_ * 16 + (lane >> 2);                            \
            const int cs_ = (lane & 3) ^ (r_ & 3);                           \
            gl_lds16(Ab + (size_t)r_ * NI + k0_ + cs_ * 8, &As[b][g_ * 16][0]); \
        }                                                                    \
        _Pragma("unroll")                                                    \
        for (int i = 0; i < 4; ++i) {                                        \
            const int g_ = wave * 4 + i;                                     \
            const int r_ = g_ * 8 + (lane >> 3);                             \
            const int cs_ = (lane & 7) ^ (r_ & 7);                           \
            gl_lds16(Bb + (size_t)r_ * NI + k0_ + cs_ * 4, &Bs[b][g_ * 8][0]); \
        }                                                                    \
    } while (0)

    STAGE_DN(0, 0);

    for (int kt = 0; kt < KT; ++kt) {
        const int cur = kt & 1;
        if (kt + 1 < KT) {
            STAGE_DN(kt + 1, cur ^ 1);
            asm volatile("s_waitcnt vmcnt(6)" ::: "memory");
        } else {
            asm volatile("s_waitcnt vmcnt(0)" ::: "memory");
        }
        __builtin_amdgcn_s_barrier();

        short8 af[4], bf[4];
        #pragma unroll
        for (int m = 0; m < 4; ++m) {
            const int R = wr * 64 + m * 16 + frow;
            af[m] = *(const short8*)&As[cur][R][ca * 8];
        }
        #pragma unroll
        for (int n = 0; n < 4; ++n) {
            const int R = wc * 64 + n * 16 + frow;
            bf[n] = frag8(*(const floatx4*)&Bs[cur][R][c0 * 4],
                          *(const floatx4*)&Bs[cur][R][c1 * 4]);
        }
        #pragma unroll
        for (int m = 0; m < 4; ++m)
            #pragma unroll
            for (int n = 0; n < 4; ++n)
                acc[m][n] = __builtin_amdgcn_mfma_f32_16x16x32_bf16(
                    af[m], bf[n], acc[m][n], 0, 0, 0);

        asm volatile("s_waitcnt lgkmcnt(0)" ::: "memory");
        __builtin_amdgcn_sched_barrier(0);
        __builtin_amdgcn_s_barrier();
    }
#undef STAGE_DN

    const int ccol  = lane & 15;
    const int crow0 = (lane >> 4) * 4;
    float* Ob = out + ((size_t)e * NT + (size_t)tm * 128) * NH + tn * 128;
    #pragma unroll
    for (int m = 0; m < 4; ++m)
        #pragma unroll
        for (int n = 0; n < 4; ++n)
            #pragma unroll
            for (int j = 0; j < 4; ++j) {
                const int row = wr * 64 + m * 16 + crow0 + j;
                const int col = wc * 64 + n * 16 + ccol;
                Ob[(size_t)row * NH + col] = acc[m][n][j];
            }
}

extern "C" void kernel_launch(void* const* d_in, const int* in_sizes, int n_in,
                              void* d_out, int out_size, void* d_ws, size_t ws_size,
                              hipStream_t stream) {
    const float* rin  = (const float*)d_in[0];
    const float* gate = (const float*)d_in[1];
    const float* up   = (const float*)d_in[2];
    const float* down = (const float*)d_in[3];
    float* out = (float*)d_out;
    ushort* hidden = (ushort*)d_ws;   // [E,T,I] bf16, 24 MB

    moe_gateup<<<dim3(1536), dim3(256), 0, stream>>>(rin, gate, up, hidden);
    moe_down<<<dim3(2048), dim3(256), 0, stream>>>(hidden, down, out);
}